// Round 2
// baseline (1157.278 us; speedup 1.0000x reference)
//
#include <hip/hip_runtime.h>

#define NBATCH 16
#define CH 512
#define HID 32
#define KTOP 153
#define SP 4096
#define NELEM (NBATCH*CH*SP)   // 33554432

typedef __bf16 bf16x8 __attribute__((ext_vector_type(8)));
typedef float f32x16 __attribute__((ext_vector_type(16)));

__device__ __forceinline__ unsigned short f2bf(float f) {
    union { float f; unsigned u; } v; v.f = f;
    unsigned r = v.u + 0x7FFFu + ((v.u >> 16) & 1u);   // RNE
    return (unsigned short)(r >> 16);
}

// ---------------------------------------------------------------------------
// K1: pure spatial reduce. One wave per (b, branch, ch). (unchanged)
// ---------------------------------------------------------------------------
__global__ __launch_bounds__(256) void k1_reduce(
    const float* __restrict__ xt, const float* __restrict__ xc,
    float* __restrict__ psum)
{
    int c4 = blockIdx.x, bz = blockIdx.y;
    int b = bz >> 1, br = bz & 1;
    const float* x = br ? xc : xt;
    int t = threadIdx.x, lane = t & 63, w = t >> 6;
    int ch = c4 * 4 + w;
    const float4* p = (const float4*)(x + ((size_t)b * CH + ch) * SP);
    float s = 0.f;
    #pragma unroll
    for (int k = 0; k < 16; ++k) {
        float4 v = p[lane + k * 64];
        s += ((v.x + v.y) + (v.z + v.w));
    }
    #pragma unroll
    for (int off = 32; off; off >>= 1) s += __shfl_xor(s, off, 64);
    if (lane == 0) psum[(size_t)(br * 16 + b) * CH + ch] = s;
}

// ---------------------------------------------------------------------------
// K2a: SE MLP + sigmoid + exact top-153 mask. (unchanged)
// ---------------------------------------------------------------------------
__global__ __launch_bounds__(512) void k2_se(
    const float* __restrict__ psum,
    const float* __restrict__ w1t, const float* __restrict__ b1t,
    const float* __restrict__ w2t, const float* __restrict__ b2t,
    const float* __restrict__ w1c, const float* __restrict__ b1c,
    const float* __restrict__ w2c, const float* __restrict__ b2c,
    float* __restrict__ sAt, float* __restrict__ sBt, float* __restrict__ attc)
{
    int b = blockIdx.x, br = blockIdx.y;
    int bb = br * 16 + b;
    int t = threadIdx.x;
    __shared__ float satt[512];
    __shared__ float ph[16][33];
    __shared__ float sh[32];
    __shared__ float sval[512];

    satt[t] = psum[(size_t)bb * CH + t] * (1.0f / 4096.0f);
    __syncthreads();

    const float* w1 = br ? w1c : w1t; const float* b1 = br ? b1c : b1t;
    const float* w2 = br ? w2c : w2t; const float* b2 = br ? b2c : b2t;

    {
        int j = t & 31, seg = t >> 5;
        float hp = 0.f;
        #pragma unroll
        for (int i = 0; i < 32; ++i)
            hp += satt[seg * 32 + i] * w1[(seg * 32 + i) * HID + j];
        ph[seg][j] = hp;
    }
    __syncthreads();
    if (t < HID) {
        float h = b1[t];
        #pragma unroll
        for (int sgi = 0; sgi < 16; ++sgi) h += ph[sgi][t];
        sh[t] = fmaxf(h, 0.0f);
    }
    __syncthreads();

    float z = b2[t];
    #pragma unroll
    for (int j = 0; j < HID; ++j) z += sh[j] * w2[j * CH + t];
    float a = 1.0f / (1.0f + expf(-z));

    if (br == 0) {
        sval[t] = a;
        __syncthreads();
        int cnt = 0;
        for (int j = 0; j < CH; ++j) {
            float o = sval[j];
            cnt += (o > a) || (o == a && j < t);   // matches top_k tie order
        }
        sAt[b * CH + t] = a;
        sBt[b * CH + t] = (cnt < KTOP) ? 1.0f : 0.0f;
    } else {
        attc[b * CH + t] = a;
    }
}

// ---------------------------------------------------------------------------
// K2b: softmax rows of cross_att -> bf16 W, pre-swizzled A granules. (unchanged)
// granule(m,k8): pos = ((kb*16 + (m>>5))*2 + ks)*64 + hi*32 + (m&31)
// ---------------------------------------------------------------------------
__global__ __launch_bounds__(64) void k2_softmax(
    const float* __restrict__ ca, unsigned short* __restrict__ wswz)
{
    int trow = blockIdx.x;
    int lane = threadIdx.x;
    const float* row = ca + (size_t)trow * CH;
    float v[8];
    #pragma unroll
    for (int i = 0; i < 8; ++i) v[i] = row[lane * 8 + i];
    float m = v[0];
    #pragma unroll
    for (int i = 1; i < 8; ++i) m = fmaxf(m, v[i]);
    #pragma unroll
    for (int off = 32; off; off >>= 1) m = fmaxf(m, __shfl_xor(m, off, 64));
    float s = 0.f;
    #pragma unroll
    for (int i = 0; i < 8; ++i) { v[i] = expf(v[i] - m); s += v[i]; }
    #pragma unroll
    for (int off = 32; off; off >>= 1) s += __shfl_xor(s, off, 64);
    float inv = 1.0f / s;

    int k = lane * 8;
    int kb = k >> 5, ks = (k >> 4) & 1, hi = (k >> 3) & 1;
    int p = ((kb * 16 + (trow >> 5)) * 2 + ks) * 64 + hi * 32 + (trow & 31);
    unsigned short* dst = wswz + (size_t)p * 8;
    ushort4 lo, hm;
    lo.x = f2bf(v[0] * inv); lo.y = f2bf(v[1] * inv);
    lo.z = f2bf(v[2] * inv); lo.w = f2bf(v[3] * inv);
    hm.x = f2bf(v[4] * inv); hm.y = f2bf(v[5] * inv);
    hm.z = f2bf(v[6] * inv); hm.w = f2bf(v[7] * inv);
    *(ushort4*)dst = lo;
    *(ushort4*)(dst + 4) = hm;
}

// ---------------------------------------------------------------------------
// K3: persistent dual-branch GEMM + epilogue with CROSS-TILE PIPELINE.
// 256 blocks (1/CU) x 512 thr (8 waves, 2/SIMD). Each block: 8 consecutive
// 32-col tiles, LDS double-buffered (2 x 2src x 32n x 512k bf16 = 128 KiB).
// Per tile: issue next tile's 16 float4 stage loads (regs) -> K-loop on
// current buffer (hides ~900cy HBM latency under ~3000cy) -> convert+write
// other buffer -> epilogue -> single barrier. sched_barrier(0) pins the
// stage-issue ahead of the K-loop.
// ---------------------------------------------------------------------------
__global__ __launch_bounds__(512, 2) void k3_fused(
    const float* __restrict__ xt, const float* __restrict__ xc,
    const unsigned short* __restrict__ wswz,
    const float* __restrict__ sAt, const float* __restrict__ sBt,
    const float* __restrict__ attc,
    float* __restrict__ out)
{
    int blk = blockIdx.x;
    int b = blk >> 4, tg = blk & 15;          // 16 blocks per batch, 256 cols each
    int t = threadIdx.x, lane = t & 63, w = t >> 6;

    __shared__ unsigned short B2[2][2][32 * 512];   // [buf][src][n][k], 128 KiB

    // staging mapping: a = n-quad, sc = source, cq -> 4 k-quads (q = chb*32+cq)
    int a  = t & 7;
    int sc = (t >> 3) & 1;
    int cq = t >> 4;                           // 0..31
    const float* xsrc = sc ? xc : xt;
    const float* gstage = xsrc + (size_t)b * CH * SP + tg * 256 + a * 4;

    // K-loop constants (A granules in shorts: kb*16384 + mb*1024 + ks*512 + lane*8)
    const unsigned short* abase = wswz + (size_t)(w * 2) * 1024 + lane * 8;
    int nb = (lane & 31) * 1024;
    int xr = (lane & 7) << 4;
    int kf = (lane >> 5) * 16;

    // ---- prologue: stage tile 0 into buf 0 ----
    {
        float4 sv[16];
        #pragma unroll
        for (int chb = 0; chb < 4; ++chb)
            #pragma unroll
            for (int r2 = 0; r2 < 4; ++r2) {
                int ch = (chb * 32 + cq) * 4 + r2;
                sv[chb * 4 + r2] = *(const float4*)(gstage + (size_t)ch * SP);
            }
        char* bl = (char*)B2[0][sc];
        #pragma unroll
        for (int chb = 0; chb < 4; ++chb) {
            int q = chb * 32 + cq;
            #pragma unroll
            for (int j = 0; j < 4; ++j) {
                int n = a * 4 + j;
                ushort4 d;
                d.x = f2bf(((const float*)&sv[chb * 4 + 0])[j]);
                d.y = f2bf(((const float*)&sv[chb * 4 + 1])[j]);
                d.z = f2bf(((const float*)&sv[chb * 4 + 2])[j]);
                d.w = f2bf(((const float*)&sv[chb * 4 + 3])[j]);
                *(ushort4*)(bl + n * 1024 + ((q * 8) ^ ((n & 7) << 4))) = d;
            }
        }
    }
    __syncthreads();

    #pragma unroll 1
    for (int i = 0; i < 8; ++i) {
        int buf = i & 1;
        int n0 = tg * 256 + i * 32;

        // ---- issue stage loads for tile i+1 (in flight across K-loop) ----
        float4 sv[16];
        if (i < 7) {
            const float* g = gstage + (i + 1) * 32;
            #pragma unroll
            for (int chb = 0; chb < 4; ++chb)
                #pragma unroll
                for (int r2 = 0; r2 < 4; ++r2) {
                    int ch = (chb * 32 + cq) * 4 + r2;
                    sv[chb * 4 + r2] = *(const float4*)(g + (size_t)ch * SP);
                }
        }
        __builtin_amdgcn_sched_barrier(0);   // pin load-issue before K-loop

        // ---- K-loop on buf ----
        f32x16 acct[2], accc[2];
        #pragma unroll
        for (int r = 0; r < 2; ++r)
            #pragma unroll
            for (int e = 0; e < 16; ++e) { acct[r][e] = 0.0f; accc[r][e] = 0.0f; }

        const char* btl = (const char*)B2[buf][0];
        const char* bcl = (const char*)B2[buf][1];

        bf16x8 afr[2][4];
        #pragma unroll
        for (int r = 0; r < 2; ++r)
            #pragma unroll
            for (int ks = 0; ks < 2; ++ks)
                afr[0][r * 2 + ks] = *(const bf16x8*)(abase + r * 1024 + ks * 512);

        #pragma unroll
        for (int kb = 0; kb < 16; ++kb) {
            int cur = kb & 1, nxt = cur ^ 1;
            if (kb < 15) {
                #pragma unroll
                for (int r = 0; r < 2; ++r)
                    #pragma unroll
                    for (int ks = 0; ks < 2; ++ks)
                        afr[nxt][r * 2 + ks] =
                            *(const bf16x8*)(abase + (kb + 1) * 16384 + r * 1024 + ks * 512);
            }
            bf16x8 bft[2], bfc[2];
            #pragma unroll
            for (int ks = 0; ks < 2; ++ks) {
                int off = nb + ((kb * 64 + ks * 32 + kf) ^ xr);
                bft[ks] = *(const bf16x8*)(btl + off);
                bfc[ks] = *(const bf16x8*)(bcl + off);
            }
            #pragma unroll
            for (int ks = 0; ks < 2; ++ks)
                #pragma unroll
                for (int r = 0; r < 2; ++r) {
                    acct[r] = __builtin_amdgcn_mfma_f32_32x32x16_bf16(
                        afr[cur][r * 2 + ks], bfc[ks], acct[r], 0, 0, 0);
                    accc[r] = __builtin_amdgcn_mfma_f32_32x32x16_bf16(
                        afr[cur][r * 2 + ks], bft[ks], accc[r], 0, 0, 0);
                }
        }

        // ---- convert + write tile i+1 into other buffer ----
        if (i < 7) {
            char* bl = (char*)B2[buf ^ 1][sc];
            #pragma unroll
            for (int chb = 0; chb < 4; ++chb) {
                int q = chb * 32 + cq;
                #pragma unroll
                for (int j = 0; j < 4; ++j) {
                    int n = a * 4 + j;
                    ushort4 d;
                    d.x = f2bf(((const float*)&sv[chb * 4 + 0])[j]);
                    d.y = f2bf(((const float*)&sv[chb * 4 + 1])[j]);
                    d.z = f2bf(((const float*)&sv[chb * 4 + 2])[j]);
                    d.w = f2bf(((const float*)&sv[chb * 4 + 3])[j]);
                    *(ushort4*)(bl + n * 1024 + ((q * 8) ^ ((n & 7) << 4))) = d;
                }
            }
        }

        // ---- epilogue tile i: C/D row=(reg&3)+8*(reg>>2)+4*(lane>>5), col=lane&31
        int colb = n0 + (lane & 31);
        int rowq = 4 * (lane >> 5);
        #pragma unroll
        for (int r = 0; r < 2; ++r) {
            #pragma unroll
            for (int reg = 0; reg < 16; ++reg) {
                int m = w * 64 + r * 32 + (reg & 3) + 8 * (reg >> 2) + rowq;
                size_t idx = ((size_t)b * CH + m) * SP + colb;
                float at = sAt[b * CH + m];
                float bt = sBt[b * CH + m];
                float ac = attc[b * CH + m];
                float ot = at * xt[idx] + bt * acct[r][reg];
                float oc = ac * xc[idx] + ac * accc[r][reg];
                __builtin_nontemporal_store(ot, &out[idx]);
                __builtin_nontemporal_store(oc, &out[NELEM + idx]);
            }
        }
        __syncthreads();
    }
}

// ---------------------------------------------------------------------------
extern "C" void kernel_launch(void* const* d_in, const int* in_sizes, int n_in,
                              void* d_out, int out_size, void* d_ws, size_t ws_size,
                              hipStream_t stream)
{
    const float* xt  = (const float*)d_in[0];
    const float* xc  = (const float*)d_in[1];
    const float* w1t = (const float*)d_in[2];
    const float* b1t = (const float*)d_in[3];
    const float* w2t = (const float*)d_in[4];
    const float* b2t = (const float*)d_in[5];
    const float* w1c = (const float*)d_in[6];
    const float* b1c = (const float*)d_in[7];
    const float* w2c = (const float*)d_in[8];
    const float* b2c = (const float*)d_in[9];
    const float* ca  = (const float*)d_in[10];
    float* out = (float*)d_out;
    char* ws = (char*)d_ws;

    unsigned short* wswz = (unsigned short*)(ws);              // 512 KiB
    float* psum = (float*)(ws + 524288ull);                    // 64 KiB
    float* sAt  = (float*)(ws + 589824ull);                    // 32 KiB
    float* sBt  = (float*)(ws + 622592ull);                    // 32 KiB
    float* attc = (float*)(ws + 655360ull);                    // 32 KiB

    hipLaunchKernelGGL(k1_reduce, dim3(128, 32), dim3(256), 0, stream,
                       xt, xc, psum);
    hipLaunchKernelGGL(k2_se, dim3(16, 2), dim3(512), 0, stream,
                       psum, w1t, b1t, w2t, b2t, w1c, b1c, w2c, b2c, sAt, sBt, attc);
    hipLaunchKernelGGL(k2_softmax, dim3(512), dim3(64), 0, stream, ca, wswz);
    hipLaunchKernelGGL(k3_fused, dim3(256), dim3(512), 0, stream,
                       xt, xc, wswz, sAt, sBt, attc, out);
}

// Round 3
// 580.608 us; speedup vs baseline: 1.9932x; 1.9932x over previous
//
#include <hip/hip_runtime.h>

#define NBATCH 16
#define CH 512
#define HID 32
#define KTOP 153
#define SP 4096
#define NELEM (NBATCH*CH*SP)   // 33554432

typedef __bf16 bf16x8 __attribute__((ext_vector_type(8)));
typedef float f32x16 __attribute__((ext_vector_type(16)));

__device__ __forceinline__ unsigned short f2bf(float f) {
    union { float f; unsigned u; } v; v.f = f;
    unsigned r = v.u + 0x7FFFu + ((v.u >> 16) & 1u);   // RNE
    return (unsigned short)(r >> 16);
}

// ---------------------------------------------------------------------------
// K1: pure spatial reduce. One wave per (b, branch, ch). (unchanged)
// ---------------------------------------------------------------------------
__global__ __launch_bounds__(256) void k1_reduce(
    const float* __restrict__ xt, const float* __restrict__ xc,
    float* __restrict__ psum)
{
    int c4 = blockIdx.x, bz = blockIdx.y;
    int b = bz >> 1, br = bz & 1;
    const float* x = br ? xc : xt;
    int t = threadIdx.x, lane = t & 63, w = t >> 6;
    int ch = c4 * 4 + w;
    const float4* p = (const float4*)(x + ((size_t)b * CH + ch) * SP);
    float s = 0.f;
    #pragma unroll
    for (int k = 0; k < 16; ++k) {
        float4 v = p[lane + k * 64];
        s += ((v.x + v.y) + (v.z + v.w));
    }
    #pragma unroll
    for (int off = 32; off; off >>= 1) s += __shfl_xor(s, off, 64);
    if (lane == 0) psum[(size_t)(br * 16 + b) * CH + ch] = s;
}

// ---------------------------------------------------------------------------
// K2a: SE MLP + sigmoid + exact top-153 mask. (unchanged)
// ---------------------------------------------------------------------------
__global__ __launch_bounds__(512) void k2_se(
    const float* __restrict__ psum,
    const float* __restrict__ w1t, const float* __restrict__ b1t,
    const float* __restrict__ w2t, const float* __restrict__ b2t,
    const float* __restrict__ w1c, const float* __restrict__ b1c,
    const float* __restrict__ w2c, const float* __restrict__ b2c,
    float* __restrict__ sAt, float* __restrict__ sBt, float* __restrict__ attc)
{
    int b = blockIdx.x, br = blockIdx.y;
    int bb = br * 16 + b;
    int t = threadIdx.x;
    __shared__ float satt[512];
    __shared__ float ph[16][33];
    __shared__ float sh[32];
    __shared__ float sval[512];

    satt[t] = psum[(size_t)bb * CH + t] * (1.0f / 4096.0f);
    __syncthreads();

    const float* w1 = br ? w1c : w1t; const float* b1 = br ? b1c : b1t;
    const float* w2 = br ? w2c : w2t; const float* b2 = br ? b2c : b2t;

    {
        int j = t & 31, seg = t >> 5;
        float hp = 0.f;
        #pragma unroll
        for (int i = 0; i < 32; ++i)
            hp += satt[seg * 32 + i] * w1[(seg * 32 + i) * HID + j];
        ph[seg][j] = hp;
    }
    __syncthreads();
    if (t < HID) {
        float h = b1[t];
        #pragma unroll
        for (int sgi = 0; sgi < 16; ++sgi) h += ph[sgi][t];
        sh[t] = fmaxf(h, 0.0f);
    }
    __syncthreads();

    float z = b2[t];
    #pragma unroll
    for (int j = 0; j < HID; ++j) z += sh[j] * w2[j * CH + t];
    float a = 1.0f / (1.0f + expf(-z));

    if (br == 0) {
        sval[t] = a;
        __syncthreads();
        int cnt = 0;
        for (int j = 0; j < CH; ++j) {
            float o = sval[j];
            cnt += (o > a) || (o == a && j < t);   // matches top_k tie order
        }
        sAt[b * CH + t] = a;
        sBt[b * CH + t] = (cnt < KTOP) ? 1.0f : 0.0f;
    } else {
        attc[b * CH + t] = a;
    }
}

// ---------------------------------------------------------------------------
// K2b: softmax rows of cross_att -> bf16 W, pre-swizzled A granules. (unchanged)
// granule(m,k8): pos = ((kb*16 + (m>>5))*2 + ks)*64 + hi*32 + (m&31)
// ---------------------------------------------------------------------------
__global__ __launch_bounds__(64) void k2_softmax(
    const float* __restrict__ ca, unsigned short* __restrict__ wswz)
{
    int trow = blockIdx.x;
    int lane = threadIdx.x;
    const float* row = ca + (size_t)trow * CH;
    float v[8];
    #pragma unroll
    for (int i = 0; i < 8; ++i) v[i] = row[lane * 8 + i];
    float m = v[0];
    #pragma unroll
    for (int i = 1; i < 8; ++i) m = fmaxf(m, v[i]);
    #pragma unroll
    for (int off = 32; off; off >>= 1) m = fmaxf(m, __shfl_xor(m, off, 64));
    float s = 0.f;
    #pragma unroll
    for (int i = 0; i < 8; ++i) { v[i] = expf(v[i] - m); s += v[i]; }
    #pragma unroll
    for (int off = 32; off; off >>= 1) s += __shfl_xor(s, off, 64);
    float inv = 1.0f / s;

    int k = lane * 8;
    int kb = k >> 5, ks = (k >> 4) & 1, hi = (k >> 3) & 1;
    int p = ((kb * 16 + (trow >> 5)) * 2 + ks) * 64 + hi * 32 + (trow & 31);
    unsigned short* dst = wswz + (size_t)p * 8;
    ushort4 lo, hm;
    lo.x = f2bf(v[0] * inv); lo.y = f2bf(v[1] * inv);
    lo.z = f2bf(v[2] * inv); lo.w = f2bf(v[3] * inv);
    hm.x = f2bf(v[4] * inv); hm.y = f2bf(v[5] * inv);
    hm.z = f2bf(v[6] * inv); hm.w = f2bf(v[7] * inv);
    *(ushort4*)dst = lo;
    *(ushort4*)(dst + 4) = hm;
}

// ---------------------------------------------------------------------------
// K3: dual-branch GEMM + epilogue, OCCUPANCY-FIRST (round-1 locality, half-M
// blocks for <=128 regs -> 16 waves/CU).
// grid 4096: lane8=id&7, half=(id>>3)&1, tile=(id>>4)*8+lane8.
//   -> m-half siblings are 8 apart: same XCD (mod-8), co-resident, so the
//      duplicate tile stage of the sibling is an L2 hit (one HBM fetch/tile).
// Block: 512 thr (8 waves), each wave one 32-row m-block of its 256-row half.
// LDS 64 KiB: [src][n=32][k=512] bf16, XOR-swizzled -> 2 blocks/CU.
// acc = 2 x f32x16 = 32 regs; launch_bounds(512,4) caps regs at 128.
// Epilogue re-reads fp32 x (staged by this block moments ago -> L1/L2 hit).
// ---------------------------------------------------------------------------
__global__ __launch_bounds__(512, 4) void k3_fused(
    const float* __restrict__ xt, const float* __restrict__ xc,
    const unsigned short* __restrict__ wswz,
    const float* __restrict__ sAt, const float* __restrict__ sBt,
    const float* __restrict__ attc,
    float* __restrict__ out)
{
    int id = blockIdx.x;
    int lane8 = id & 7, half = (id >> 3) & 1, pslot = id >> 4;
    int tile = pslot * 8 + lane8;            // 0..2047
    int b = tile >> 7, nt = tile & 127;
    int t = threadIdx.x, lane = t & 63, w = t >> 6;
    int n0 = nt * 32;

    __shared__ unsigned short B2[2][32 * 512];   // [src][n][k] bf16 swizzled, 64 KiB

    // ---- stage: thread owns (n-quad a, source sc, ch-quad cq) ----
    {
        int a  = t & 7;
        int sc = (t >> 3) & 1;
        int cq = t >> 4;                      // 0..31
        const float* xsrc = sc ? xc : xt;
        const float* gbase = xsrc + (size_t)b * CH * SP + n0 + a * 4;
        char* bl = (char*)B2[sc];
        #pragma unroll
        for (int chb = 0; chb < 4; ++chb) {
            int q = chb * 32 + cq;            // k-quad 0..127
            float4 v0 = *(const float4*)(gbase + (size_t)(q * 4 + 0) * SP);
            float4 v1 = *(const float4*)(gbase + (size_t)(q * 4 + 1) * SP);
            float4 v2 = *(const float4*)(gbase + (size_t)(q * 4 + 2) * SP);
            float4 v3 = *(const float4*)(gbase + (size_t)(q * 4 + 3) * SP);
            #pragma unroll
            for (int j = 0; j < 4; ++j) {
                int n = a * 4 + j;
                ushort4 d;
                d.x = f2bf(((const float*)&v0)[j]);
                d.y = f2bf(((const float*)&v1)[j]);
                d.z = f2bf(((const float*)&v2)[j]);
                d.w = f2bf(((const float*)&v3)[j]);
                *(ushort4*)(bl + n * 1024 + ((q * 8) ^ ((n & 7) << 4))) = d;
            }
        }
    }
    __syncthreads();

    // ---- GEMM: this wave's m-block mb = half*8 + w (32 rows) ----
    int mb = half * 8 + w;

    f32x16 acct, accc;
    #pragma unroll
    for (int e = 0; e < 16; ++e) { acct[e] = 0.0f; accc[e] = 0.0f; }

    // A granule (kb,ks): wswz + kb*16384 + mb*1024 + ks*512 + lane*8  (shorts)
    const unsigned short* abase = wswz + mb * 1024 + (size_t)lane * 8;
    const char* btl = (const char*)B2[0];
    const char* bcl = (const char*)B2[1];
    int nb = (lane & 31) * 1024;
    int xr = (lane & 7) << 4;
    int kf = (lane >> 5) * 16;

    bf16x8 afr[2][2];
    #pragma unroll
    for (int ks = 0; ks < 2; ++ks)
        afr[0][ks] = *(const bf16x8*)(abase + ks * 512);

    #pragma unroll
    for (int kb = 0; kb < 16; ++kb) {
        int cur = kb & 1, nxt = cur ^ 1;
        if (kb < 15) {
            #pragma unroll
            for (int ks = 0; ks < 2; ++ks)
                afr[nxt][ks] = *(const bf16x8*)(abase + (kb + 1) * 16384 + ks * 512);
        }
        bf16x8 bft[2], bfc[2];
        #pragma unroll
        for (int ks = 0; ks < 2; ++ks) {
            int off = nb + ((kb * 64 + ks * 32 + kf) ^ xr);
            bft[ks] = *(const bf16x8*)(btl + off);
            bfc[ks] = *(const bf16x8*)(bcl + off);
        }
        #pragma unroll
        for (int ks = 0; ks < 2; ++ks) {
            acct = __builtin_amdgcn_mfma_f32_32x32x16_bf16(
                afr[cur][ks], bfc[ks], acct, 0, 0, 0);
            accc = __builtin_amdgcn_mfma_f32_32x32x16_bf16(
                afr[cur][ks], bft[ks], accc, 0, 0, 0);
        }
    }

    // ---- epilogue: C/D row=(reg&3)+8*(reg>>2)+4*(lane>>5), col=lane&31 ----
    int colb = n0 + (lane & 31);
    int rowq = 4 * (lane >> 5);
    int mbase = mb * 32;
    #pragma unroll
    for (int reg = 0; reg < 16; ++reg) {
        int m = mbase + (reg & 3) + 8 * (reg >> 2) + rowq;
        size_t idx = ((size_t)b * CH + m) * SP + colb;
        float at = sAt[b * CH + m];
        float bt = sBt[b * CH + m];
        float ac = attc[b * CH + m];
        float ot = at * xt[idx] + bt * acct[reg];
        float oc = ac * (xc[idx] + accc[reg]);
        __builtin_nontemporal_store(ot, &out[idx]);
        __builtin_nontemporal_store(oc, &out[NELEM + idx]);
    }
}

// ---------------------------------------------------------------------------
extern "C" void kernel_launch(void* const* d_in, const int* in_sizes, int n_in,
                              void* d_out, int out_size, void* d_ws, size_t ws_size,
                              hipStream_t stream)
{
    const float* xt  = (const float*)d_in[0];
    const float* xc  = (const float*)d_in[1];
    const float* w1t = (const float*)d_in[2];
    const float* b1t = (const float*)d_in[3];
    const float* w2t = (const float*)d_in[4];
    const float* b2t = (const float*)d_in[5];
    const float* w1c = (const float*)d_in[6];
    const float* b1c = (const float*)d_in[7];
    const float* w2c = (const float*)d_in[8];
    const float* b2c = (const float*)d_in[9];
    const float* ca  = (const float*)d_in[10];
    float* out = (float*)d_out;
    char* ws = (char*)d_ws;

    unsigned short* wswz = (unsigned short*)(ws);              // 512 KiB
    float* psum = (float*)(ws + 524288ull);                    // 64 KiB
    float* sAt  = (float*)(ws + 589824ull);                    // 32 KiB
    float* sBt  = (float*)(ws + 622592ull);                    // 32 KiB
    float* attc = (float*)(ws + 655360ull);                    // 32 KiB

    hipLaunchKernelGGL(k1_reduce, dim3(128, 32), dim3(256), 0, stream,
                       xt, xc, psum);
    hipLaunchKernelGGL(k2_se, dim3(16, 2), dim3(512), 0, stream,
                       psum, w1t, b1t, w2t, b2t, w1c, b1c, w2c, b2c, sAt, sBt, attc);
    hipLaunchKernelGGL(k2_softmax, dim3(512), dim3(64), 0, stream, ca, wswz);
    hipLaunchKernelGGL(k3_fused, dim3(4096), dim3(512), 0, stream,
                       xt, xc, wswz, sAt, sBt, attc, out);
}